// Round 5
// baseline (6970.921 us; speedup 1.0000x reference)
//
#include <hip/hip_runtime.h>
#include <hip/hip_bf16.h>

#define B_ 128
#define T_ 200
#define H_ 512
#define G_ 2048   // 4*H
#define E_ 300

typedef unsigned short u16;
typedef unsigned int u32;

using f32x4 = __attribute__((ext_vector_type(4))) float;
using s16x8 = __attribute__((ext_vector_type(8))) short;
using u32x4 = __attribute__((ext_vector_type(4))) u32;

__device__ __forceinline__ u16 f2bf(float f) {
  u32 u = __builtin_bit_cast(u32, f);
  u32 r = (u + 0x7fffu + ((u >> 16) & 1u)) >> 16;   // RNE
  return (u16)r;
}
__device__ __forceinline__ float bf2f(u16 s) {
  return __builtin_bit_cast(float, (u32)s << 16);
}

// ---- device-coherent (L1/L2-bypass) memory ops ----------------------------
__device__ __forceinline__ u32x4 ld_u32x4_sc(const void* p) {
  u32x4 r;
  asm volatile("global_load_dwordx4 %0, %1, off sc0 sc1" : "=v"(r) : "v"(p));
  return r;
}
__device__ __forceinline__ void st_u32_sc(void* p, u32 v) {
  asm volatile("global_store_dword %0, %1, off sc0 sc1" :: "v"(p), "v"(v));
}

// ---------------------------------------------------------------------------
// Wih (4H x E f32) -> bf16 padded [4H x 320]
// ---------------------------------------------------------------------------
__global__ __launch_bounds__(256) void wih_cvt(
    const float* __restrict__ W, u16* __restrict__ Wb)
{
  const int idx = blockIdx.x * 256 + threadIdx.x;   // 2048*320 total
  const int row = idx / 320, k = idx - row * 320;
  const float v = (k < E_) ? W[row * E_ + k] : 0.f;
  Wb[idx] = f2bf(v);
}

// ---------------------------------------------------------------------------
// xg = emb[tok] @ Wih^T + bih + bhh  (round-4 version, known-good ~160us)
// ---------------------------------------------------------------------------
__global__ __launch_bounds__(256) void xg_gemm(
    const int* __restrict__ tok, const float* __restrict__ emb,
    const u16* __restrict__ Wb, const float* __restrict__ bih,
    const float* __restrict__ bhh, u16* __restrict__ xg)
{
  __shared__ u16 Al[64 * 320];
  __shared__ u16 Bl[32 * 320];
  __shared__ int tks[64];
  const int tid = threadIdx.x;
  const int m0 = blockIdx.x * 64;
  if (tid < 64) tks[tid] = tok[m0 + tid];
  __syncthreads();
  {
    const int row = tid >> 2, part = tid & 3;
    const float* erow = emb + (size_t)tks[row] * E_;
    char* base = (char*)Al + row * 640;
    const int swz = (row & 7) << 4;
#pragma unroll
    for (int i = 0; i < 40; ++i) {
      const int kw = part * 40 + i;
      const int k = kw * 2;
      const float v0 = (k < E_) ? erow[k] : 0.f;
      const float v1 = (k + 1 < E_) ? erow[k + 1] : 0.f;
      *(u32*)(base + ((kw * 4) ^ swz)) = (u32)f2bf(v0) | ((u32)f2bf(v1) << 16);
    }
  }
  __syncthreads();
  const int wv = tid >> 6, ln = tid & 63, lr = ln & 15, lq = ln >> 4;
  const int arow = wv * 16 + lr;
  const char* abase = (const char*)Al + arow * 640;
  const int aswz = (arow & 7) << 4;
  const int brow = tid >> 3, bpart = tid & 7;
  char* bdst = (char*)Bl + brow * 640;
  const int bswz = (brow & 7) << 4;
  const char* b0base = (const char*)Bl + lr * 640;
  const char* b1base = (const char*)Bl + (16 + lr) * 640;
  const int bswz2 = (lr & 7) << 4;

  for (int ni = 0; ni < 8; ++ni) {
    const int n0 = blockIdx.y * 256 + ni * 32;
    {
      const u16* src = Wb + (size_t)(n0 + brow) * 320 + bpart * 40;
#pragma unroll
      for (int i = 0; i < 5; ++i) {
        s16x8 v = *(const s16x8*)(src + i * 8);
        *(s16x8*)(bdst + (((bpart * 5 + i) * 16) ^ bswz)) = v;
      }
    }
    __syncthreads();
    f32x4 acc0 = {0.f, 0.f, 0.f, 0.f}, acc1 = {0.f, 0.f, 0.f, 0.f};
#pragma unroll
    for (int ks = 0; ks < 10; ++ks) {
      const int kb = ks * 64 + lq * 16;
      s16x8 af  = *(const s16x8*)(abase  + (kb ^ aswz));
      s16x8 bf0 = *(const s16x8*)(b0base + (kb ^ bswz2));
      s16x8 bf1 = *(const s16x8*)(b1base + (kb ^ bswz2));
      acc0 = __builtin_amdgcn_mfma_f32_16x16x32_bf16(af, bf0, acc0, 0, 0, 0);
      acc1 = __builtin_amdgcn_mfma_f32_16x16x32_bf16(af, bf1, acc1, 0, 0, 0);
    }
#pragma unroll
    for (int r = 0; r < 4; ++r) {
      const int m = m0 + wv * 16 + lq * 4 + r;
      const int gA = n0 + lr;
      const int gB = n0 + 16 + lr;
      xg[(size_t)m * G_ + gA] = f2bf(acc0[r] + bih[gA] + bhh[gA]);
      xg[(size_t)m * G_ + gB] = f2bf(acc1[r] + bih[gB] + bhh[gB]);
    }
    __syncthreads();
  }
}

// ---------------------------------------------------------------------------
// Persistent LSTM recurrence, v4: tag-in-data sync (no flags, no drains).
// 64 WGs x 512 thr. WG = (grp, jt). 8 waves = (bt 0..3) x (kh 0..1).
// h exchanged as u32 = (bf16<<16) | tag16, tag = TAGB + t, via 3 rotating
// coherent buffers. Consumers re-load their own fragment until all 64 tags
// match — ONE one-way latency on the critical path. Intra-WG K-reduction via
// parity-double-buffered LDS red (closes kh1-overwrite race).
// Safety chain (3 bufs): storing h_{t+3} requires validating h_{t+2}, which
// requires every same-group WG stored h_{t+2} (post its barrier of step t+1),
// which is after it validated+read h_t — so h_t's buffer is dead. Stale data
// from a previous call carries the same tag AND identical bits (deterministic
// replay), so early acceptance is benign. 0xAA poison never matches a tag.
// ---------------------------------------------------------------------------
template<int TRACK_C>
__global__ __launch_bounds__(512, 2) void lstm_rec(
    const int* __restrict__ tok, const u16* __restrict__ xg,
    const float* __restrict__ Whh, u32* __restrict__ h32,
    const float* __restrict__ c0in, float* __restrict__ cOut,
    float* __restrict__ mhOut)
{
  __shared__ f32x4 red[2][4][4][64];   // 32 KB, parity-buffered
  const u32 TAGB = 1u + (TRACK_C ? 0u : 256u);
  const int tid = threadIdx.x;
  const int wv = tid >> 6, ln = tid & 63, lr = ln & 15, lq = ln >> 4;
  const int bt = wv >> 1, kh = wv & 1;
  const int grp = (int)blockIdx.x >> 5, jt = (int)blockIdx.x & 31;
  const int j0 = jt * 16, bg0 = grp * 64;
  const int BH = B_ * H_;

  // persistent B fragments: Bf[q][ks] = Whh[q*512+j0+lr][kh*256+ks*32+lq*8 ..+8]
  s16x8 Bf[4][8];
#pragma unroll
  for (int q = 0; q < 4; ++q) {
    const float* wr = Whh + (size_t)(q * H_ + j0 + lr) * H_ + kh * 256 + lq * 8;
#pragma unroll
    for (int ks = 0; ks < 8; ++ks) {
      const float* wp = wr + ks * 32;
      s16x8 f;
#pragma unroll
      for (int i = 0; i < 8; ++i) f[i] = (short)f2bf(wp[i]);
      Bf[q][ks] = f;
    }
  }

  float c[4], mb[4];
#pragma unroll
  for (int r = 0; r < 4; ++r) {
    const int b = bg0 + bt * 16 + lq * 4 + r;
    float cv = 0.f;
    if (!TRACK_C) cv = c0in[b * H_ + j0 + lr];
    c[r] = cv;
    mb[r] = TRACK_C ? cv : 0.f;
  }

  // prologue: publish h_0 = 0 with tag TAGB into buffer 0 (kh0 waves own rows)
  if (kh == 0) {
#pragma unroll
    for (int r = 0; r < 4; ++r) {
      const int b = bg0 + bt * 16 + lq * 4 + r;
      st_u32_sc(h32 + (size_t)b * H_ + j0 + lr, TAGB);
    }
  }

  int cur = 0;
  for (int t = 0; t < T_; ++t) {
    const int nxt = (cur == 2) ? 0 : cur + 1;

    // prefetch xg + tok (cached; complete during first validate wait)
    float gx[4][4];
    int tk[4];
    if (kh == 0) {
#pragma unroll
      for (int r = 0; r < 4; ++r) {
        const int b = bg0 + bt * 16 + lq * 4 + r;
        tk[r] = tok[b * T_ + t];
        const size_t xo = ((size_t)b * T_ + t) * G_ + j0 + lr;
#pragma unroll
        for (int q = 0; q < 4; ++q) gx[q][r] = bf2f(xg[xo + q * H_]);
      }
    }

    // ---- tagged h_t load+validate: this wave's own fragment bytes only ----
    const u32 tag = TAGB + (u32)t;
    const u32* hsrc = h32 + (size_t)cur * BH
                      + (size_t)(bg0 + bt * 16 + lr) * H_ + kh * 256 + lq * 8;
    u32x4 hv[16];
    {
      int guard = 0;
      for (;;) {
#pragma unroll
        for (int i = 0; i < 16; ++i)
          hv[i] = ld_u32x4_sc(hsrc + (i >> 1) * 32 + (i & 1) * 4);
        asm volatile("s_waitcnt vmcnt(0)" ::: "memory");
        u32 bad = 0;
#pragma unroll
        for (int i = 0; i < 16; ++i)
#pragma unroll
          for (int e = 0; e < 4; ++e) bad |= (hv[i][e] ^ tag) & 0xFFFFu;
        if (__all(bad == 0)) break;
        if (++guard > (1 << 20)) break;     // bail out instead of hanging
        __builtin_amdgcn_s_sleep(1);
      }
    }
    __builtin_amdgcn_sched_barrier(0);

    // pack top-16 bf16 halves -> A-fragments
    f32x4 acc[4];
#pragma unroll
    for (int q = 0; q < 4; ++q) acc[q] = (f32x4){0.f, 0.f, 0.f, 0.f};
#pragma unroll
    for (int ks = 0; ks < 8; ++ks) {
      u32x4 w;
      w[0] = (hv[2 * ks][0] >> 16) | (hv[2 * ks][1] & 0xFFFF0000u);
      w[1] = (hv[2 * ks][2] >> 16) | (hv[2 * ks][3] & 0xFFFF0000u);
      w[2] = (hv[2 * ks + 1][0] >> 16) | (hv[2 * ks + 1][1] & 0xFFFF0000u);
      w[3] = (hv[2 * ks + 1][2] >> 16) | (hv[2 * ks + 1][3] & 0xFFFF0000u);
      const s16x8 af = __builtin_bit_cast(s16x8, w);
#pragma unroll
      for (int q = 0; q < 4; ++q)
        acc[q] = __builtin_amdgcn_mfma_f32_16x16x32_bf16(af, Bf[q][ks], acc[q], 0, 0, 0);
    }

    if (kh == 1) {
#pragma unroll
      for (int q = 0; q < 4; ++q) red[t & 1][bt][q][ln] = acc[q];
    }
    __syncthreads();                         // red ready (also orders h reads)
    if (kh == 0) {
#pragma unroll
      for (int q = 0; q < 4; ++q) acc[q] += red[t & 1][bt][q][ln];
      const bool last = (t == T_ - 1);
      const u32 ntag = TAGB + (u32)(t + 1);
      u32* hdst = h32 + (size_t)nxt * BH;
#pragma unroll
      for (int r = 0; r < 4; ++r) {
        const int b = bg0 + bt * 16 + lq * 4 + r;
        const float gi = acc[0][r] + gx[0][r];
        const float gf = acc[1][r] + gx[1][r];
        const float gg = acc[2][r] + gx[2][r];
        const float go = acc[3][r] + gx[3][r];
        const float si = 1.f / (1.f + __expf(-gi));
        const float sf = 1.f / (1.f + __expf(-gf));
        const float so = 1.f / (1.f + __expf(-go));
        const float tg = 2.f / (1.f + __expf(-2.f * gg)) - 1.f;
        const float cn = sf * c[r] + si * tg;
        const float tc = 2.f / (1.f + __expf(-2.f * cn)) - 1.f;
        const float hn = so * tc;
        c[r] = cn;
        if (tk[r] != 0) mb[r] = TRACK_C ? cn : hn;
        if (!last)
          st_u32_sc(hdst + (size_t)b * H_ + j0 + lr,
                    ((u32)f2bf(hn) << 16) | ntag);   // fire-and-forget
      }
    }
    cur = nxt;
  }

  if (kh == 0) {
#pragma unroll
    for (int r = 0; r < 4; ++r) {
      const int b = bg0 + bt * 16 + lq * 4 + r;
      if (TRACK_C) cOut[b * H_ + j0 + lr] = mb[r];
      else         mhOut[b * H_ + j0 + lr] = mb[r];
    }
  }
}

// ---------------------------------------------------------------------------
// head: logits = [mh, sim] @ fcW^T + fcb ; log_softmax
// ---------------------------------------------------------------------------
__global__ __launch_bounds__(128) void final_k(
    const float* __restrict__ mh, const float* __restrict__ sim,
    const float* __restrict__ fcW, const float* __restrict__ fcb,
    float* __restrict__ out)
{
  const int b = threadIdx.x;
  float l[3];
#pragma unroll
  for (int cc = 0; cc < 3; ++cc) {
    const float* wr = fcW + cc * (H_ + 1);
    float s = fcb[cc] + sim[b] * wr[H_];
    for (int j = 0; j < H_; ++j) s += mh[b * H_ + j] * wr[j];
    l[cc] = s;
  }
  const float m = fmaxf(l[0], fmaxf(l[1], l[2]));
  const float lse = m + logf(__expf(l[0] - m) + __expf(l[1] - m) + __expf(l[2] - m));
  out[b * 3 + 0] = l[0] - lse;
  out[b * 3 + 1] = l[1] - lse;
  out[b * 3 + 2] = l[2] - lse;
}

extern "C" void kernel_launch(void* const* d_in, const int* in_sizes, int n_in,
                              void* d_out, int out_size, void* d_ws, size_t ws_size,
                              hipStream_t stream) {
  const int*   prem = (const int*)d_in[0];
  const int*   hypo = (const int*)d_in[1];
  const float* sim  = (const float*)d_in[2];
  const float* emb  = (const float*)d_in[3];
  const float* WihP = (const float*)d_in[4];
  const float* WhhP = (const float*)d_in[5];
  const float* bihP = (const float*)d_in[6];
  const float* bhhP = (const float*)d_in[7];
  const float* WihH = (const float*)d_in[8];
  const float* WhhH = (const float*)d_in[9];
  const float* bihH = (const float*)d_in[10];
  const float* bhhH = (const float*)d_in[11];
  const float* fcW  = (const float*)d_in[12];
  const float* fcb  = (const float*)d_in[13];
  float* out = (float*)d_out;

  char* ws = (char*)d_ws;
  const size_t XG_BYTES = (size_t)B_ * T_ * G_ * 2;       // 104,857,600
  const size_t H32_OFF = XG_BYTES;                        // 3 x 128 x 512 u32
  const size_t CL_OFF  = H32_OFF + (size_t)3 * B_ * H_ * 4;
  const size_t MH_OFF  = CL_OFF + (size_t)B_ * H_ * 4;
  const size_t WB_OFF  = MH_OFF + (size_t)B_ * H_ * 4;
  const size_t NEED    = WB_OFF + (size_t)G_ * 320 * 2;   // ~107.3 MB
  if (ws_size < NEED) return;  // visible failure instead of OOB corruption

  u16*   xg    = (u16*)ws;
  u32*   h32   = (u32*)(ws + H32_OFF);
  float* cLast = (float*)(ws + CL_OFF);
  float* mh    = (float*)(ws + MH_OFF);
  u16*   Wb    = (u16*)(ws + WB_OFF);

  dim3 gG(400, 8);
  wih_cvt<<<2560, 256, 0, stream>>>(WihP, Wb);
  xg_gemm<<<gG, 256, 0, stream>>>(prem, emb, Wb, bihP, bhhP, xg);
  lstm_rec<1><<<64, 512, 0, stream>>>(prem, xg, WhhP, h32, nullptr, cLast, nullptr);
  wih_cvt<<<2560, 256, 0, stream>>>(WihH, Wb);
  xg_gemm<<<gG, 256, 0, stream>>>(hypo, emb, Wb, bihH, bhhH, xg);
  lstm_rec<0><<<64, 512, 0, stream>>>(hypo, xg, WhhH, h32, cLast, nullptr, mh);
  final_k<<<1, 128, 0, stream>>>(mh, sim, fcW, fcb, out);
}

// Round 6
// 5108.973 us; speedup vs baseline: 1.3644x; 1.3644x over previous
//
#include <hip/hip_runtime.h>
#include <hip/hip_bf16.h>

#define B_ 128
#define T_ 200
#define H_ 512
#define G_ 2048   // 4*H
#define E_ 300

typedef unsigned short u16;
typedef unsigned int u32;

using f32x4 = __attribute__((ext_vector_type(4))) float;
using s16x8 = __attribute__((ext_vector_type(8))) short;
using u32x2 = __attribute__((ext_vector_type(2))) u32;

__device__ __forceinline__ u16 f2bf(float f) {
  u32 u = __builtin_bit_cast(u32, f);
  u32 r = (u + 0x7fffu + ((u >> 16) & 1u)) >> 16;   // RNE
  return (u16)r;
}
__device__ __forceinline__ float bf2f(u16 s) {
  return __builtin_bit_cast(float, (u32)s << 16);
}

// ---- device-coherent (L1/L2-bypass) memory ops ----------------------------
__device__ __forceinline__ s16x8 ld_h16_sc(const void* p) {
  s16x8 r;
  asm volatile("global_load_dwordx4 %0, %1, off sc0 sc1" : "=v"(r) : "v"(p));
  return r;
}
__device__ __forceinline__ void st_h_sc(void* p, u32 v) {   // low 16 bits
  asm volatile("global_store_short %0, %1, off sc0 sc1" :: "v"(p), "v"(v));
}
__device__ __forceinline__ u32 ld_flag_sc(const void* p) {
  u32 r;
  asm volatile("global_load_dword %0, %1, off sc0 sc1\n\ts_waitcnt vmcnt(0)"
               : "=v"(r) : "v"(p) : "memory");
  return r;
}
__device__ __forceinline__ void st_flag_sc(void* p, u32 v) {
  asm volatile("global_store_dword %0, %1, off sc0 sc1" :: "v"(p), "v"(v) : "memory");
}

// ---------------------------------------------------------------------------
// Wih (4H x E f32) -> bf16 padded [4H x 320]
// ---------------------------------------------------------------------------
__global__ __launch_bounds__(256) void wih_cvt(
    const float* __restrict__ W, u16* __restrict__ Wb)
{
  const int idx = blockIdx.x * 256 + threadIdx.x;   // 2048*320 total
  const int row = idx / 320, k = idx - row * 320;
  const float v = (k < E_) ? W[row * E_ + k] : 0.f;
  Wb[idx] = f2bf(v);
}

// ---------------------------------------------------------------------------
// mask bits: mb[t*4 + w] = bit i <- (tok[(w*32+i)*T + t] != 0)
// ---------------------------------------------------------------------------
__global__ __launch_bounds__(64) void mask_k(
    const int* __restrict__ tok, u32* __restrict__ mb)
{
  const int idx = blockIdx.x * 64 + threadIdx.x;
  if (idx >= T_ * 4) return;
  const int t = idx >> 2, w = idx & 3;
  u32 bits = 0;
  for (int i = 0; i < 32; ++i)
    bits |= (tok[(w * 32 + i) * T_ + t] != 0 ? 1u : 0u) << i;
  mb[idx] = bits;
}

// ---------------------------------------------------------------------------
// xg GEMM, output layout xg[m][j 512][q 4] bf16 with m = t*128 + b.
// Tile 64(M) x 256(N), N-loop inside; A staged once; B from pre-cvt bf16 Wb.
// grid (400, 8), block 256.
// ---------------------------------------------------------------------------
__global__ __launch_bounds__(256) void xg_gemm(
    const int* __restrict__ tok, const float* __restrict__ emb,
    const u16* __restrict__ Wb, const float* __restrict__ bih,
    const float* __restrict__ bhh, u16* __restrict__ xg)
{
  __shared__ u16 Al[64 * 320];
  __shared__ u16 Bl[32 * 320];
  __shared__ int tks[64];
  const int tid = threadIdx.x;
  const int bx = blockIdx.x;
  const int m0 = bx * 64;            // m = t*128 + b ; block: t = bx>>1, b0 = (bx&1)*64
  if (tid < 64) tks[tid] = tok[((bx & 1) * 64 + tid) * T_ + (bx >> 1)];
  __syncthreads();
  {
    const int row = tid >> 2, part = tid & 3;
    const float* erow = emb + (size_t)tks[row] * E_;
    char* base = (char*)Al + row * 640;
    const int swz = (row & 7) << 4;
#pragma unroll
    for (int i = 0; i < 40; ++i) {
      const int kw = part * 40 + i;
      const int k = kw * 2;
      const float v0 = (k < E_) ? erow[k] : 0.f;
      const float v1 = (k + 1 < E_) ? erow[k + 1] : 0.f;
      *(u32*)(base + ((kw * 4) ^ swz)) = (u32)f2bf(v0) | ((u32)f2bf(v1) << 16);
    }
  }
  __syncthreads();
  const int wv = tid >> 6, ln = tid & 63, lr = ln & 15, lq = ln >> 4;
  const int arow = wv * 16 + lr;
  const char* abase = (const char*)Al + arow * 640;
  const int aswz = (arow & 7) << 4;
  const int brow = tid >> 3, bpart = tid & 7;
  char* bdst = (char*)Bl + brow * 640;
  const int bswz = (brow & 7) << 4;
  const char* b0base = (const char*)Bl + lr * 640;
  const char* b1base = (const char*)Bl + (16 + lr) * 640;
  const int bswz2 = (lr & 7) << 4;

  for (int ni = 0; ni < 8; ++ni) {
    const int n0 = blockIdx.y * 256 + ni * 32;
    {
      const u16* src = Wb + (size_t)(n0 + brow) * 320 + bpart * 40;
#pragma unroll
      for (int i = 0; i < 5; ++i) {
        s16x8 v = *(const s16x8*)(src + i * 8);
        *(s16x8*)(bdst + (((bpart * 5 + i) * 16) ^ bswz)) = v;
      }
    }
    __syncthreads();
    f32x4 acc0 = {0.f, 0.f, 0.f, 0.f}, acc1 = {0.f, 0.f, 0.f, 0.f};
#pragma unroll
    for (int ks = 0; ks < 10; ++ks) {
      const int kb = ks * 64 + lq * 16;
      s16x8 af  = *(const s16x8*)(abase  + (kb ^ aswz));
      s16x8 bf0 = *(const s16x8*)(b0base + (kb ^ bswz2));
      s16x8 bf1 = *(const s16x8*)(b1base + (kb ^ bswz2));
      acc0 = __builtin_amdgcn_mfma_f32_16x16x32_bf16(af, bf0, acc0, 0, 0, 0);
      acc1 = __builtin_amdgcn_mfma_f32_16x16x32_bf16(af, bf1, acc1, 0, 0, 0);
    }
    const int qc = n0 >> 9;            // gate quadrant (uniform per 32-tile)
    const int jA = (n0 & 511) + lr;    // j within quadrant
#pragma unroll
    for (int r = 0; r < 4; ++r) {
      const int m = m0 + wv * 16 + lq * 4 + r;
      const int gA = n0 + lr, gB = n0 + 16 + lr;
      xg[(size_t)m * 2048 + (size_t)jA * 4 + qc]        = f2bf(acc0[r] + bih[gA] + bhh[gA]);
      xg[(size_t)m * 2048 + (size_t)(jA + 16) * 4 + qc] = f2bf(acc1[r] + bih[gB] + bhh[gB]);
    }
    __syncthreads();
  }
}

// ---------------------------------------------------------------------------
// Persistent LSTM recurrence, v6: 32 WGs x 512 thr (round-3 protocol, half
// the participants). WG = (grp 0..1, jt 0..15): 64 batch x 32 j. 8 waves =
// (bp 0..1, jh 0..1, kh 0..1): wave covers b[bp*32..+32] (2 b-tiles),
// gates q*512 + j0 + jh*16 + 0..16 (Bf[4][8] = 128 VGPR), K-half kh.
// 16 flags/group, ONE wave polls; 3 barriers/step; h via sc0sc1 bf16.
// xg read as [m][j][q] dwordx2 (4 gates/cell); token mask from bitmask.
// ---------------------------------------------------------------------------
template<int TRACK_C>
__global__ __launch_bounds__(512, 2) void lstm_rec(
    const u16* __restrict__ xg, const float* __restrict__ Whh,
    u16* __restrict__ hbuf, const float* __restrict__ c0in,
    float* __restrict__ cOut, float* __restrict__ mhOut,
    u32* __restrict__ flags, const u32* __restrict__ maskb)
{
  __shared__ f32x4 red[2][2][2][4][64];   // [bp][jh][bt][q][ln] = 32 KB
  const int tid = threadIdx.x;
  const int wv = tid >> 6, ln = tid & 63, lr = ln & 15, lq = ln >> 4;
  const int bp = wv >> 2, jh = (wv >> 1) & 1, kh = wv & 1;
  const int grp = (int)blockIdx.x >> 4, jt = (int)blockIdx.x & 15;
  const int j0 = jt * 32;
  const int jbase = j0 + jh * 16;          // wave's 16 j (col = lr)
  const int b0w = grp * 64 + bp * 32;      // wave's 32 b
  u32* gflags = flags + grp * 256;         // 16 flags x 16 u32 pad

  // persistent B frags: Bf[q][ks] = Whh[q*512+jbase+lr][kh*256+ks*32+lq*8 ..+8]
  s16x8 Bf[4][8];
#pragma unroll
  for (int q = 0; q < 4; ++q) {
    const float* wr = Whh + (size_t)(q * H_ + jbase + lr) * H_ + kh * 256 + lq * 8;
#pragma unroll
    for (int ks = 0; ks < 8; ++ks) {
      const float* wp = wr + ks * 32;
      s16x8 f;
#pragma unroll
      for (int i = 0; i < 8; ++i) f[i] = (short)f2bf(wp[i]);
      Bf[q][ks] = f;
    }
  }

  float c[2][4], mb[2][4];
#pragma unroll
  for (int bt = 0; bt < 2; ++bt)
#pragma unroll
    for (int r = 0; r < 4; ++r) {
      const int b = b0w + bt * 16 + lq * 4 + r;
      float cv = 0.f;
      if (!TRACK_C) cv = c0in[b * H_ + jbase + lr];
      c[bt][r] = cv;
      mb[bt][r] = TRACK_C ? cv : 0.f;
    }

  const u32* pp = gflags + (ln & 15) * 16;   // 16 flags, x4 lane duplication
  const int mword = b0w >> 5;                // uniform per wave

  for (int t = 0; t < T_; ++t) {
    const u16* hrd = hbuf + (t & 1) * (B_ * H_);
    u16* hwr = hbuf + ((t + 1) & 1) * (B_ * H_);

    // kh0: prefetch xg (dwordx2 = 4 gates/cell) + mask word (cached loads)
    u32x2 gxp[2][4];
    u32 mku = 0;
    if (kh == 0) {
      mku = maskb[t * 4 + mword];
#pragma unroll
      for (int bt = 0; bt < 2; ++bt)
#pragma unroll
        for (int r = 0; r < 4; ++r) {
          const int b = b0w + bt * 16 + lq * 4 + r;
          const size_t eo = (size_t)(t * 128 + b) * 2048 + (size_t)(jbase + lr) * 4;
          gxp[bt][r] = *(const u32x2*)(xg + eo);
        }
    }

    // ONE wave polls the 16 producer flags of this group
    if (wv == 0 && t > 0) {
      int guard = 0;
      for (;;) {
        u32 v = ld_flag_sc(pp);
        if (__all((int)(v >= (u32)t))) break;
        if (++guard > (1 << 22)) break;     // bail out instead of hanging
        __builtin_amdgcn_s_sleep(1);
      }
    }
    __syncthreads();                         // barrier A
    __builtin_amdgcn_sched_barrier(0);

    // h_t loads (coherent): A-frag row = lane&15, k = (lane>>4)*8+i (+32/ks)
    s16x8 ha[2][8];
#pragma unroll
    for (int bt = 0; bt < 2; ++bt) {
      const u16* hb = hrd + (size_t)(b0w + bt * 16 + lr) * H_ + kh * 256 + lq * 8;
#pragma unroll
      for (int ks = 0; ks < 8; ++ks) ha[bt][ks] = ld_h16_sc(hb + ks * 32);
    }
    asm volatile("s_waitcnt vmcnt(0)" ::: "memory");
    __builtin_amdgcn_sched_barrier(0);

    f32x4 acc[2][4];
#pragma unroll
    for (int bt = 0; bt < 2; ++bt)
#pragma unroll
      for (int q = 0; q < 4; ++q) acc[bt][q] = (f32x4){0.f, 0.f, 0.f, 0.f};
#pragma unroll
    for (int ks = 0; ks < 8; ++ks)
#pragma unroll
      for (int bt = 0; bt < 2; ++bt)
#pragma unroll
        for (int q = 0; q < 4; ++q)
          acc[bt][q] = __builtin_amdgcn_mfma_f32_16x16x32_bf16(
              ha[bt][ks], Bf[q][ks], acc[bt][q], 0, 0, 0);

    if (kh == 1) {
#pragma unroll
      for (int bt = 0; bt < 2; ++bt)
#pragma unroll
        for (int q = 0; q < 4; ++q) red[bp][jh][bt][q][ln] = acc[bt][q];
    }
    __syncthreads();                         // barrier B
    if (kh == 0) {
      const bool last = (t == T_ - 1);
#pragma unroll
      for (int bt = 0; bt < 2; ++bt) {
#pragma unroll
        for (int q = 0; q < 4; ++q) acc[bt][q] += red[bp][jh][bt][q][ln];
#pragma unroll
        for (int r = 0; r < 4; ++r) {
          const int b = b0w + bt * 16 + lq * 4 + r;
          const u32 lo = gxp[bt][r][0], hi = gxp[bt][r][1];
          const float gi = acc[bt][0][r] + bf2f((u16)lo);
          const float gf = acc[bt][1][r] + bf2f((u16)(lo >> 16));
          const float gG = acc[bt][2][r] + bf2f((u16)hi);
          const float go = acc[bt][3][r] + bf2f((u16)(hi >> 16));
          const float si = 1.f / (1.f + __expf(-gi));
          const float sf = 1.f / (1.f + __expf(-gf));
          const float so = 1.f / (1.f + __expf(-go));
          const float tg = 2.f / (1.f + __expf(-2.f * gG)) - 1.f;
          const float cn = sf * c[bt][r] + si * tg;
          const float tc = 2.f / (1.f + __expf(-2.f * cn)) - 1.f;
          const float hn = so * tc;
          c[bt][r] = cn;
          if ((mku >> (bt * 16 + lq * 4 + r)) & 1u) mb[bt][r] = TRACK_C ? cn : hn;
          if (!last) st_h_sc(hwr + (size_t)b * H_ + jbase + lr, (u32)f2bf(hn));
        }
      }
      if (!last) asm volatile("s_waitcnt vmcnt(0)" ::: "memory");  // drain h
    }
    __syncthreads();                         // barrier C
    if (tid == 0 && t + 1 < T_) st_flag_sc(gflags + jt * 16, (u32)(t + 1));
  }

  if (kh == 0) {
#pragma unroll
    for (int bt = 0; bt < 2; ++bt)
#pragma unroll
      for (int r = 0; r < 4; ++r) {
        const int b = b0w + bt * 16 + lq * 4 + r;
        if (TRACK_C) cOut[b * H_ + jbase + lr] = mb[bt][r];
        else         mhOut[b * H_ + jbase + lr] = mb[bt][r];
      }
  }
}

// ---------------------------------------------------------------------------
// head: logits = [mh, sim] @ fcW^T + fcb ; log_softmax
// ---------------------------------------------------------------------------
__global__ __launch_bounds__(128) void final_k(
    const float* __restrict__ mh, const float* __restrict__ sim,
    const float* __restrict__ fcW, const float* __restrict__ fcb,
    float* __restrict__ out)
{
  const int b = threadIdx.x;
  float l[3];
#pragma unroll
  for (int cc = 0; cc < 3; ++cc) {
    const float* wr = fcW + cc * (H_ + 1);
    float s = fcb[cc] + sim[b] * wr[H_];
    for (int j = 0; j < H_; ++j) s += mh[b * H_ + j] * wr[j];
    l[cc] = s;
  }
  const float m = fmaxf(l[0], fmaxf(l[1], l[2]));
  const float lse = m + logf(__expf(l[0] - m) + __expf(l[1] - m) + __expf(l[2] - m));
  out[b * 3 + 0] = l[0] - lse;
  out[b * 3 + 1] = l[1] - lse;
  out[b * 3 + 2] = l[2] - lse;
}

extern "C" void kernel_launch(void* const* d_in, const int* in_sizes, int n_in,
                              void* d_out, int out_size, void* d_ws, size_t ws_size,
                              hipStream_t stream) {
  const int*   prem = (const int*)d_in[0];
  const int*   hypo = (const int*)d_in[1];
  const float* sim  = (const float*)d_in[2];
  const float* emb  = (const float*)d_in[3];
  const float* WihP = (const float*)d_in[4];
  const float* WhhP = (const float*)d_in[5];
  const float* bihP = (const float*)d_in[6];
  const float* bhhP = (const float*)d_in[7];
  const float* WihH = (const float*)d_in[8];
  const float* WhhH = (const float*)d_in[9];
  const float* bihH = (const float*)d_in[10];
  const float* bhhH = (const float*)d_in[11];
  const float* fcW  = (const float*)d_in[12];
  const float* fcb  = (const float*)d_in[13];
  float* out = (float*)d_out;

  char* ws = (char*)d_ws;
  const size_t XG_BYTES = (size_t)B_ * T_ * G_ * 2;       // 104,857,600
  const size_t HB_OFF = XG_BYTES;                         // 2 x 128 x 512 bf16
  const size_t CL_OFF = HB_OFF + (size_t)2 * B_ * H_ * 2;
  const size_t MH_OFF = CL_OFF + (size_t)B_ * H_ * 4;
  const size_t FL_OFF = MH_OFF + (size_t)B_ * H_ * 4;     // 2 x 4 KB flags
  const size_t MK_OFF = FL_OFF + 8192;                    // 2 x 4 KB maskbits
  const size_t WB_OFF = MK_OFF + 8192;
  const size_t NEED   = WB_OFF + (size_t)G_ * 320 * 2;    // ~107 MB
  if (ws_size < NEED) return;  // visible failure instead of OOB corruption

  u16*   xg    = (u16*)ws;
  u16*   hbuf  = (u16*)(ws + HB_OFF);
  float* cLast = (float*)(ws + CL_OFF);
  float* mh    = (float*)(ws + MH_OFF);
  u32*   flagsP = (u32*)(ws + FL_OFF);        // 2 grp x 16 x 64B
  u32*   flagsH = flagsP + 1024;
  u32*   maskbP = (u32*)(ws + MK_OFF);        // 200 x 4 u32
  u32*   maskbH = maskbP + 1024;
  u16*   Wb    = (u16*)(ws + WB_OFF);

  hipMemsetAsync(ws + FL_OFF, 0, 8192, stream);           // both flag regions

  dim3 gG(400, 8);
  wih_cvt<<<2560, 256, 0, stream>>>(WihP, Wb);
  mask_k<<<13, 64, 0, stream>>>(prem, maskbP);
  xg_gemm<<<gG, 256, 0, stream>>>(prem, emb, Wb, bihP, bhhP, xg);
  hipMemsetAsync(hbuf, 0, (size_t)B_ * H_ * 2, stream);   // h0 = 0 (buffer 0)
  lstm_rec<1><<<32, 512, 0, stream>>>(xg, WhhP, hbuf, nullptr, cLast, nullptr, flagsP, maskbP);
  wih_cvt<<<2560, 256, 0, stream>>>(WihH, Wb);
  mask_k<<<13, 64, 0, stream>>>(hypo, maskbH);
  xg_gemm<<<gG, 256, 0, stream>>>(hypo, emb, Wb, bihH, bhhH, xg);
  hipMemsetAsync(hbuf, 0, (size_t)B_ * H_ * 2, stream);   // h0 = 0 (buffer 0)
  lstm_rec<0><<<32, 512, 0, stream>>>(xg, WhhH, hbuf, cLast, nullptr, mh, flagsH, maskbH);
  final_k<<<1, 128, 0, stream>>>(mh, sim, fcW, fcb, out);
}

// Round 7
// 2575.116 us; speedup vs baseline: 2.7070x; 1.9840x over previous
//
#include <hip/hip_runtime.h>
#include <hip/hip_bf16.h>

#define B_ 128
#define T_ 200
#define H_ 512
#define G_ 2048   // 4*H
#define E_ 300

typedef unsigned short u16;
typedef unsigned int u32;

using f32x4 = __attribute__((ext_vector_type(4))) float;
using s16x8 = __attribute__((ext_vector_type(8))) short;
using u32x2 = __attribute__((ext_vector_type(2))) u32;

__device__ __forceinline__ u16 f2bf(float f) {
  u32 u = __builtin_bit_cast(u32, f);
  u32 r = (u + 0x7fffu + ((u >> 16) & 1u)) >> 16;   // RNE
  return (u16)r;
}
__device__ __forceinline__ float bf2f(u16 s) {
  return __builtin_bit_cast(float, (u32)s << 16);
}

// ---- device-coherent (L1/L2-bypass) memory ops ----------------------------
__device__ __forceinline__ s16x8 ld_h16_sc(const void* p) {
  s16x8 r;
  asm volatile("global_load_dwordx4 %0, %1, off sc0 sc1" : "=v"(r) : "v"(p));
  return r;
}
__device__ __forceinline__ void st_h_sc(void* p, u32 v) {   // low 16 bits
  asm volatile("global_store_short %0, %1, off sc0 sc1" :: "v"(p), "v"(v));
}
__device__ __forceinline__ u32 ld_flag_sc(const void* p) {
  u32 r;
  asm volatile("global_load_dword %0, %1, off sc0 sc1\n\ts_waitcnt vmcnt(0)"
               : "=v"(r) : "v"(p) : "memory");
  return r;
}
__device__ __forceinline__ void st_flag_sc(void* p, u32 v) {
  asm volatile("global_store_dword %0, %1, off sc0 sc1" :: "v"(p), "v"(v) : "memory");
}

// ---------------------------------------------------------------------------
// Wih (4H x E f32) -> bf16 padded [4H x 320]
// ---------------------------------------------------------------------------
__global__ __launch_bounds__(256) void wih_cvt(
    const float* __restrict__ W, u16* __restrict__ Wb)
{
  const int idx = blockIdx.x * 256 + threadIdx.x;   // 2048*320 total
  const int row = idx / 320, k = idx - row * 320;
  const float v = (k < E_) ? W[row * E_ + k] : 0.f;
  Wb[idx] = f2bf(v);
}

// ---------------------------------------------------------------------------
// mask bits: mb[t*4 + w] = bit i <- (tok[(w*32+i)*T + t] != 0)
// ---------------------------------------------------------------------------
__global__ __launch_bounds__(64) void mask_k(
    const int* __restrict__ tok, u32* __restrict__ mb)
{
  const int idx = blockIdx.x * 64 + threadIdx.x;
  if (idx >= T_ * 4) return;
  const int t = idx >> 2, w = idx & 3;
  u32 bits = 0;
  for (int i = 0; i < 32; ++i)
    bits |= (tok[(w * 32 + i) * T_ + t] != 0 ? 1u : 0u) << i;
  mb[idx] = bits;
}

// ---------------------------------------------------------------------------
// xg GEMM, output layout xg[m][j 512][q 4] bf16 with m = t*128 + b.
// Tile 64(M) x 256(N), N-loop inside; A staged once; B from pre-cvt bf16 Wb.
// grid (400, 8), block 256.  (verified end-to-end in round 6)
// ---------------------------------------------------------------------------
__global__ __launch_bounds__(256) void xg_gemm(
    const int* __restrict__ tok, const float* __restrict__ emb,
    const u16* __restrict__ Wb, const float* __restrict__ bih,
    const float* __restrict__ bhh, u16* __restrict__ xg)
{
  __shared__ u16 Al[64 * 320];
  __shared__ u16 Bl[32 * 320];
  __shared__ int tks[64];
  const int tid = threadIdx.x;
  const int bx = blockIdx.x;
  const int m0 = bx * 64;            // m = t*128 + b ; block: t = bx>>1, b0 = (bx&1)*64
  if (tid < 64) tks[tid] = tok[((bx & 1) * 64 + tid) * T_ + (bx >> 1)];
  __syncthreads();
  {
    const int row = tid >> 2, part = tid & 3;
    const float* erow = emb + (size_t)tks[row] * E_;
    char* base = (char*)Al + row * 640;
    const int swz = (row & 7) << 4;
#pragma unroll
    for (int i = 0; i < 40; ++i) {
      const int kw = part * 40 + i;
      const int k = kw * 2;
      const float v0 = (k < E_) ? erow[k] : 0.f;
      const float v1 = (k + 1 < E_) ? erow[k + 1] : 0.f;
      *(u32*)(base + ((kw * 4) ^ swz)) = (u32)f2bf(v0) | ((u32)f2bf(v1) << 16);
    }
  }
  __syncthreads();
  const int wv = tid >> 6, ln = tid & 63, lr = ln & 15, lq = ln >> 4;
  const int arow = wv * 16 + lr;
  const char* abase = (const char*)Al + arow * 640;
  const int aswz = (arow & 7) << 4;
  const int brow = tid >> 3, bpart = tid & 7;
  char* bdst = (char*)Bl + brow * 640;
  const int bswz = (brow & 7) << 4;
  const char* b0base = (const char*)Bl + lr * 640;
  const char* b1base = (const char*)Bl + (16 + lr) * 640;
  const int bswz2 = (lr & 7) << 4;

  for (int ni = 0; ni < 8; ++ni) {
    const int n0 = blockIdx.y * 256 + ni * 32;
    {
      const u16* src = Wb + (size_t)(n0 + brow) * 320 + bpart * 40;
#pragma unroll
      for (int i = 0; i < 5; ++i) {
        s16x8 v = *(const s16x8*)(src + i * 8);
        *(s16x8*)(bdst + (((bpart * 5 + i) * 16) ^ bswz)) = v;
      }
    }
    __syncthreads();
    f32x4 acc0 = {0.f, 0.f, 0.f, 0.f}, acc1 = {0.f, 0.f, 0.f, 0.f};
#pragma unroll
    for (int ks = 0; ks < 10; ++ks) {
      const int kb = ks * 64 + lq * 16;
      s16x8 af  = *(const s16x8*)(abase  + (kb ^ aswz));
      s16x8 bf0 = *(const s16x8*)(b0base + (kb ^ bswz2));
      s16x8 bf1 = *(const s16x8*)(b1base + (kb ^ bswz2));
      acc0 = __builtin_amdgcn_mfma_f32_16x16x32_bf16(af, bf0, acc0, 0, 0, 0);
      acc1 = __builtin_amdgcn_mfma_f32_16x16x32_bf16(af, bf1, acc1, 0, 0, 0);
    }
    const int qc = n0 >> 9;            // gate quadrant (uniform per 32-tile)
    const int jA = (n0 & 511) + lr;    // j within quadrant
#pragma unroll
    for (int r = 0; r < 4; ++r) {
      const int m = m0 + wv * 16 + lq * 4 + r;
      const int gA = n0 + lr, gB = n0 + 16 + lr;
      xg[(size_t)m * 2048 + (size_t)jA * 4 + qc]        = f2bf(acc0[r] + bih[gA] + bhh[gA]);
      xg[(size_t)m * 2048 + (size_t)(jA + 16) * 4 + qc] = f2bf(acc1[r] + bih[gB] + bhh[gB]);
    }
    __syncthreads();
  }
}

// ---------------------------------------------------------------------------
// Persistent LSTM recurrence, v7 = round-3 structure (best measured) with
// off-critical-path improvements only:
//  - xg read as one u32x2 per cell from [t*128+b][j*4+q] layout
//  - token mask from precomputed bitmask (1 uniform word / wave / step)
// 64 WGs x 512 thr. WG = (grp 0..1, jt 0..31): 64 b x 16 j. 8 waves =
// (bt 0..3, kh 0..1): 16 b x 16 j x half-K, 32 MFMA/wave/step.
// Whh B-frags in VGPRs. 32 flags/group, ONE wave polls; 3 barriers/step.
// ---------------------------------------------------------------------------
template<int TRACK_C>
__global__ __launch_bounds__(512, 2) void lstm_rec(
    const u16* __restrict__ xg, const float* __restrict__ Whh,
    u16* __restrict__ hbuf, const float* __restrict__ c0in,
    float* __restrict__ cOut, float* __restrict__ mhOut,
    u32* __restrict__ flags, const u32* __restrict__ maskb)
{
  __shared__ f32x4 red[4][4][64];   // 16 KB partial-sum exchange
  const int tid = threadIdx.x;
  const int wv = tid >> 6, ln = tid & 63, lr = ln & 15, lq = ln >> 4;
  const int bt = wv >> 1, kh = wv & 1;
  const int grp = (int)blockIdx.x >> 5, jt = (int)blockIdx.x & 31;
  const int j0 = jt * 16, bg0 = grp * 64;
  u32* gflags = flags + grp * 512;          // 32 flags x 16 u32 pad

  // persistent B fragments: Bf[q][ks] = Whh[q*512+j0+lr][kh*256+ks*32+lq*8 ..+8]
  s16x8 Bf[4][8];
#pragma unroll
  for (int q = 0; q < 4; ++q) {
    const float* wr = Whh + (size_t)(q * H_ + j0 + lr) * H_ + kh * 256 + lq * 8;
#pragma unroll
    for (int ks = 0; ks < 8; ++ks) {
      const float* wp = wr + ks * 32;
      s16x8 f;
#pragma unroll
      for (int i = 0; i < 8; ++i) f[i] = (short)f2bf(wp[i]);
      Bf[q][ks] = f;
    }
  }

  float c[4], mb[4];
#pragma unroll
  for (int r = 0; r < 4; ++r) {
    const int b = bg0 + bt * 16 + lq * 4 + r;
    float cv = 0.f;
    if (!TRACK_C) cv = c0in[b * H_ + j0 + lr];
    c[r] = cv;
    mb[r] = TRACK_C ? cv : 0.f;
  }

  const u32* pp = gflags + (ln & 31) * 16;   // 32 flags, x2 lane duplication
  const int mword = (bg0 + bt * 16) >> 5;    // uniform per wave
  const int mshift = (bt & 1) * 16;

  for (int t = 0; t < T_; ++t) {
    const u16* hrd = hbuf + (t & 1) * (B_ * H_);
    u16* hwr = hbuf + ((t + 1) & 1) * (B_ * H_);

    // kh0: prefetch xg (u32x2 = 4 gates/cell) + mask word (cached loads;
    // latency hides under the poll)
    u32x2 gxp[4];
    u32 mku = 0;
    if (kh == 0) {
      mku = maskb[t * 4 + mword] >> mshift;
#pragma unroll
      for (int r = 0; r < 4; ++r) {
        const int b = bg0 + bt * 16 + lq * 4 + r;
        gxp[r] = *(const u32x2*)(xg + (size_t)(t * 128 + b) * 2048
                                    + (size_t)(j0 + lr) * 4);
      }
    }

    // ONE wave polls the 32 producer flags of this group
    if (wv == 0 && t > 0) {
      int guard = 0;
      for (;;) {
        u32 v = ld_flag_sc(pp);
        if (__all((int)(v >= (u32)t))) break;
        if (++guard > (1 << 22)) break;     // bail out instead of hanging
        __builtin_amdgcn_s_sleep(1);
      }
    }
    __syncthreads();                         // barrier A
    __builtin_amdgcn_sched_barrier(0);

    // h_t loads (coherent): A-frag row = lane&15, k = (lane>>4)*8+i (+32/ks)
    s16x8 ha[8];
    const u16* hb = hrd + (size_t)(bg0 + bt * 16 + lr) * H_ + kh * 256 + lq * 8;
#pragma unroll
    for (int ks = 0; ks < 8; ++ks) ha[ks] = ld_h16_sc(hb + ks * 32);
    asm volatile("s_waitcnt vmcnt(0)" ::: "memory");
    __builtin_amdgcn_sched_barrier(0);

    f32x4 acc[4];
#pragma unroll
    for (int q = 0; q < 4; ++q) acc[q] = (f32x4){0.f, 0.f, 0.f, 0.f};
#pragma unroll
    for (int ks = 0; ks < 8; ++ks)
#pragma unroll
      for (int q = 0; q < 4; ++q)
        acc[q] = __builtin_amdgcn_mfma_f32_16x16x32_bf16(ha[ks], Bf[q][ks], acc[q], 0, 0, 0);

    if (kh == 1) {
#pragma unroll
      for (int q = 0; q < 4; ++q) red[bt][q][ln] = acc[q];
    }
    __syncthreads();                         // barrier B
    if (kh == 0) {
#pragma unroll
      for (int q = 0; q < 4; ++q) acc[q] += red[bt][q][ln];
      const bool last = (t == T_ - 1);
#pragma unroll
      for (int r = 0; r < 4; ++r) {
        const int b = bg0 + bt * 16 + lq * 4 + r;
        const u32 lo = gxp[r][0], hi = gxp[r][1];
        const float gi = acc[0][r] + bf2f((u16)lo);
        const float gf = acc[1][r] + bf2f((u16)(lo >> 16));
        const float gG = acc[2][r] + bf2f((u16)hi);
        const float go = acc[3][r] + bf2f((u16)(hi >> 16));
        const float si = 1.f / (1.f + __expf(-gi));
        const float sf = 1.f / (1.f + __expf(-gf));
        const float so = 1.f / (1.f + __expf(-go));
        const float tg = 2.f / (1.f + __expf(-2.f * gG)) - 1.f;
        const float cn = sf * c[r] + si * tg;
        const float tc = 2.f / (1.f + __expf(-2.f * cn)) - 1.f;
        const float hn = so * tc;
        c[r] = cn;
        if ((mku >> (lq * 4 + r)) & 1u) mb[r] = TRACK_C ? cn : hn;
        if (!last) st_h_sc(hwr + (size_t)b * H_ + j0 + lr, (u32)f2bf(hn));
      }
      if (!last) asm volatile("s_waitcnt vmcnt(0)" ::: "memory");  // drain h
    }
    __syncthreads();                         // barrier C
    if (tid == 0 && t + 1 < T_) st_flag_sc(gflags + jt * 16, (u32)(t + 1));
  }

  if (kh == 0) {
#pragma unroll
    for (int r = 0; r < 4; ++r) {
      const int b = bg0 + bt * 16 + lq * 4 + r;
      if (TRACK_C) cOut[b * H_ + j0 + lr] = mb[r];
      else         mhOut[b * H_ + j0 + lr] = mb[r];
    }
  }
}

// ---------------------------------------------------------------------------
// head: logits = [mh, sim] @ fcW^T + fcb ; log_softmax
// ---------------------------------------------------------------------------
__global__ __launch_bounds__(128) void final_k(
    const float* __restrict__ mh, const float* __restrict__ sim,
    const float* __restrict__ fcW, const float* __restrict__ fcb,
    float* __restrict__ out)
{
  const int b = threadIdx.x;
  float l[3];
#pragma unroll
  for (int cc = 0; cc < 3; ++cc) {
    const float* wr = fcW + cc * (H_ + 1);
    float s = fcb[cc] + sim[b] * wr[H_];
    for (int j = 0; j < H_; ++j) s += mh[b * H_ + j] * wr[j];
    l[cc] = s;
  }
  const float m = fmaxf(l[0], fmaxf(l[1], l[2]));
  const float lse = m + logf(__expf(l[0] - m) + __expf(l[1] - m) + __expf(l[2] - m));
  out[b * 3 + 0] = l[0] - lse;
  out[b * 3 + 1] = l[1] - lse;
  out[b * 3 + 2] = l[2] - lse;
}

extern "C" void kernel_launch(void* const* d_in, const int* in_sizes, int n_in,
                              void* d_out, int out_size, void* d_ws, size_t ws_size,
                              hipStream_t stream) {
  const int*   prem = (const int*)d_in[0];
  const int*   hypo = (const int*)d_in[1];
  const float* sim  = (const float*)d_in[2];
  const float* emb  = (const float*)d_in[3];
  const float* WihP = (const float*)d_in[4];
  const float* WhhP = (const float*)d_in[5];
  const float* bihP = (const float*)d_in[6];
  const float* bhhP = (const float*)d_in[7];
  const float* WihH = (const float*)d_in[8];
  const float* WhhH = (const float*)d_in[9];
  const float* bihH = (const float*)d_in[10];
  const float* bhhH = (const float*)d_in[11];
  const float* fcW  = (const float*)d_in[12];
  const float* fcb  = (const float*)d_in[13];
  float* out = (float*)d_out;

  char* ws = (char*)d_ws;
  const size_t XG_BYTES = (size_t)B_ * T_ * G_ * 2;       // 104,857,600
  const size_t HB_OFF = XG_BYTES;                         // 2 x 128 x 512 bf16
  const size_t CL_OFF = HB_OFF + (size_t)2 * B_ * H_ * 2;
  const size_t MH_OFF = CL_OFF + (size_t)B_ * H_ * 4;
  const size_t FL_OFF = MH_OFF + (size_t)B_ * H_ * 4;     // 2 x 8 KB flags
  const size_t MK_OFF = FL_OFF + 16384;                   // 2 x 4 KB maskbits
  const size_t WB_OFF = MK_OFF + 8192;
  const size_t NEED   = WB_OFF + (size_t)G_ * 320 * 2;    // ~107 MB
  if (ws_size < NEED) return;  // visible failure instead of OOB corruption

  u16*   xg    = (u16*)ws;
  u16*   hbuf  = (u16*)(ws + HB_OFF);
  float* cLast = (float*)(ws + CL_OFF);
  float* mh    = (float*)(ws + MH_OFF);
  u32*   flagsP = (u32*)(ws + FL_OFF);        // 2 grp x 32 x 64B
  u32*   flagsH = flagsP + 2048;
  u32*   maskbP = (u32*)(ws + MK_OFF);        // 200 x 4 u32
  u32*   maskbH = maskbP + 1024;
  u16*   Wb    = (u16*)(ws + WB_OFF);

  hipMemsetAsync(ws + FL_OFF, 0, 16384, stream);          // both flag regions

  dim3 gG(400, 8);
  wih_cvt<<<2560, 256, 0, stream>>>(WihP, Wb);
  mask_k<<<13, 64, 0, stream>>>(prem, maskbP);
  xg_gemm<<<gG, 256, 0, stream>>>(prem, emb, Wb, bihP, bhhP, xg);
  hipMemsetAsync(hbuf, 0, (size_t)B_ * H_ * 2, stream);   // h0 = 0 (buffer 0)
  lstm_rec<1><<<64, 512, 0, stream>>>(xg, WhhP, hbuf, nullptr, cLast, nullptr, flagsP, maskbP);
  wih_cvt<<<2560, 256, 0, stream>>>(WihH, Wb);
  mask_k<<<13, 64, 0, stream>>>(hypo, maskbH);
  xg_gemm<<<gG, 256, 0, stream>>>(hypo, emb, Wb, bihH, bhhH, xg);
  hipMemsetAsync(hbuf, 0, (size_t)B_ * H_ * 2, stream);   // h0 = 0 (buffer 0)
  lstm_rec<0><<<64, 512, 0, stream>>>(xg, WhhH, hbuf, cLast, nullptr, mh, flagsH, maskbH);
  final_k<<<1, 128, 0, stream>>>(mh, sim, fcW, fcb, out);
}